// Round 8
// baseline (85.506 us; speedup 1.0000x reference)
//
#include <hip/hip_runtime.h>
#include <math.h>

#define T_LEN 8192
#define EPSF  1e-6f
#define LOG2E 1.44269504088896340736f

typedef __attribute__((ext_vector_type(8))) short short8;
typedef __attribute__((ext_vector_type(4))) float float4v;

union FragU { unsigned u[4]; short8 s; };

// funnel shift: ((hi:lo) >> s), s in {0,16} -> v_alignbit_b32
static __device__ __forceinline__ unsigned funnel(unsigned hi, unsigned lo, unsigned s) {
    return (unsigned)(((((unsigned long long)hi) << 32) | lo) >> s);
}

// ---------------------------------------------------------------------------
// One block = (batch b, 256-row t-strip), 1024 blocks, 256 thr, 4 blocks/CU,
// single dispatch round. LDS ~25 KB.
//
// Phase 0 (pre-sync): tid<80 stage x window (80 float4 -> xs); ALL threads
//   issue shapelet global loads (4 lanes/shapelet, 16 floats each).
// Phase 1 (between syncs), per thread, balanced across all waves:
//   a) prep: 4-lane groups znorm + bf16 hi/lo split shapelet p=wave*16+g,
//      shfl_xor(1,2) combines; write Bhi/Blo (b64, permuted row
//      c=(p&3)*16+(p>>2)); leader writes lsum[p], ls2'[p](*LOG2E).
//   b) stats: thread r computes window stats of row r via 17 ds_read_b128
//      + prefix/suffix edge correction; writes lstat[r]={a',amu',w2',0}
//      (log2-domain folded).
//   c) x-split: tid<80 split 4 x-values each -> xh16/xl16 (trunc hi,
//      trunc residual -- identical per-element math to R7's A-split).
// Phase 2: B frags from LDS (b128); A frags = 5 dword reads + 4 funnel
//   shifts from xh16/xl16; 3-MFMA bf16 hi/lo GEMM; epilogue
//   e2 = a'*acc - (amu'*sm_p + w2' + sv'_p), act = exp2(e2); float4 stores
//   (lane n owns cols 4n..4n+3); zero-padding fix only on edge blocks.
// ---------------------------------------------------------------------------
__global__ __launch_bounds__(256, 4) void shapelet_fused(
        const float* __restrict__ x,
        const float* __restrict__ sh,
        float* __restrict__ out) {
    __shared__ unsigned short Bhi[64][72];     // 9 KB, 144 B rows (16B-align)
    __shared__ unsigned short Blo[64][72];     // 9 KB
    __shared__ float xs[320];                  // x[t0-32 .. t0+287]
    __shared__ float4 lstat[256];              // {a', amu', w2', 0} per row
    __shared__ __align__(16) float lsum[64];   // logical-p sum(eff)
    __shared__ __align__(16) float ls2[64];    // logical-p sum(eff^2)*LOG2E
    __shared__ __align__(8) unsigned short xh16[320];
    __shared__ __align__(8) unsigned short xl16[320];

    const int tid  = threadIdx.x;
    const int lane = tid & 63;
    const int wave = tid >> 6;
    const int n    = lane & 15;
    const int quad = lane >> 4;

    const int super = blockIdx.x & 31;         // 32 strips of 256 rows
    const int b     = blockIdx.x >> 5;         // 32 batches
    const int t0    = super << 8;
    const bool edge = (super == 0) || (super == 31);

    // ---------------- phase 0 ----------------
    // xs staging: 80 float4
    if (tid < 80) {
        int g0 = t0 - 32 + (tid << 2);
        float4 v;
        if (!edge || (g0 >= 0 && g0 + 3 < T_LEN)) {
            v = *(const float4*)(x + (size_t)b * T_LEN + g0);
        } else {
            float* vp = (float*)&v;
#pragma unroll
            for (int e = 0; e < 4; ++e) {
                int g = g0 + e;
                vp[e] = ((unsigned)g < (unsigned)T_LEN) ? x[(size_t)b * T_LEN + g] : 0.f;
            }
        }
        *(float4*)&xs[tid << 2] = v;
    }
    // prep global loads: shapelet p, quarter c4 (16 floats/thread)
    const int p  = (wave << 4) + (lane >> 2);
    const int c4 = lane & 3;
    float v[16];
    {
        const float4* shv = (const float4*)sh;   // 1024 float4
#pragma unroll
        for (int i = 0; i < 4; ++i) {
            float4 f = shv[p * 16 + c4 * 4 + i];
            v[i * 4 + 0] = f.x; v[i * 4 + 1] = f.y;
            v[i * 4 + 2] = f.z; v[i * 4 + 3] = f.w;
        }
    }
    __syncthreads();

    // ---------------- phase 1a: shapelet prep ----------------
    {
        float s1 = 0.f;
#pragma unroll
        for (int j = 0; j < 16; ++j) s1 += v[j];
        s1 += __shfl_xor(s1, 1);
        s1 += __shfl_xor(s1, 2);
        float mu = s1 * (1.f / 64.f);
        float sq = 0.f;
#pragma unroll
        for (int j = 0; j < 16; ++j) { float d = v[j] - mu; sq = fmaf(d, d, sq); }
        sq += __shfl_xor(sq, 1);
        sq += __shfl_xor(sq, 2);
        float sd  = fmaxf(sqrtf(sq * (1.f / 64.f)), EPSF);
        float inv = 1.f / sd;
        const int c_row = ((p & 3) << 4) + (p >> 2);   // permuted B row
        float ssum = 0.f, ss2 = 0.f;
#pragma unroll
        for (int jj = 0; jj < 4; ++jj) {
            unsigned wh[2], wl[2];
#pragma unroll
            for (int k = 0; k < 2; ++k) {
                unsigned ph = 0, pl = 0;
#pragma unroll
                for (int e = 0; e < 2; ++e) {
                    float s = (v[jj * 4 + k * 2 + e] - mu) * inv;
                    unsigned ub = __float_as_uint(s);
                    float hi = __uint_as_float(ub & 0xFFFF0000u);
                    float lo = s - hi;
                    unsigned lb = __float_as_uint(lo) & 0xFFFF0000u;
                    ph |= (e ? (ub & 0xFFFF0000u) : (ub >> 16));
                    pl |= (e ? lb : (lb >> 16));
                    float eff = hi + __uint_as_float(lb);
                    ssum += eff;
                    ss2  = fmaf(eff, eff, ss2);
                }
                wh[k] = ph; wl[k] = pl;
            }
            *(uint2*)&Bhi[c_row][c4 * 16 + jj * 4] = make_uint2(wh[0], wh[1]);
            *(uint2*)&Blo[c_row][c4 * 16 + jj * 4] = make_uint2(wl[0], wl[1]);
        }
        ssum += __shfl_xor(ssum, 1);
        ssum += __shfl_xor(ssum, 2);
        ss2  += __shfl_xor(ss2, 1);
        ss2  += __shfl_xor(ss2, 2);
        if (c4 == 0) { lsum[p] = ssum; ls2[p] = ss2 * LOG2E; }
    }

    // ---------------- phase 1b: per-row window stats ----------------
    {
        const int r = tid;
        const int a = r >> 2, o = r & 3;
        float fullS = 0.f, fullQ = 0.f;
        float4 F0 = *(const float4*)&xs[a << 2];
        fullS += F0.x + F0.y + F0.z + F0.w;
        fullQ = fmaf(F0.x, F0.x, fmaf(F0.y, F0.y, fmaf(F0.z, F0.z, fmaf(F0.w, F0.w, fullQ))));
#pragma unroll 4
        for (int k = 1; k < 16; ++k) {
            float4 f = *(const float4*)&xs[(a + k) << 2];
            fullS += f.x + f.y + f.z + f.w;
            fullQ = fmaf(f.x, f.x, fmaf(f.y, f.y, fmaf(f.z, f.z, fmaf(f.w, f.w, fullQ))));
        }
        float4 F16 = *(const float4*)&xs[(a + 16) << 2];
        float t16S = F16.x + F16.y + F16.z + F16.w;
        float t16Q = fmaf(F16.x, F16.x, fmaf(F16.y, F16.y, fmaf(F16.z, F16.z, F16.w * F16.w)));
        fullS += t16S;
        fullQ += t16Q;
        // prefix_o: sum of first o elements
        float h0S = (o > 0 ? F0.x : 0.f) + (o > 1 ? F0.y : 0.f) + (o > 2 ? F0.z : 0.f);
        float h0Q = (o > 0 ? F0.x * F0.x : 0.f) + (o > 1 ? F0.y * F0.y : 0.f) + (o > 2 ? F0.z * F0.z : 0.f);
        float p16S = (o > 0 ? F16.x : 0.f) + (o > 1 ? F16.y : 0.f) + (o > 2 ? F16.z : 0.f);
        float p16Q = (o > 0 ? F16.x * F16.x : 0.f) + (o > 1 ? F16.y * F16.y : 0.f) + (o > 2 ? F16.z * F16.z : 0.f);
        float s1 = fullS - h0S - (t16S - p16S);
        float sq = fullQ - h0Q - (t16Q - p16Q);
        float mu  = s1 * (1.f / 64.f);
        float var = fmaxf(sq * (1.f / 64.f) - mu * mu, 0.f);
        float sd  = fmaxf(sqrtf(var), EPSF);
        float inv = 1.f / sd;
        float ap  = 2.f * inv * LOG2E;                 // alpha'
        float4 st;
        st.x = ap;
        st.y = ap * mu;                                // alphamu'
        st.z = 64.f * var * inv * inv * LOG2E;         // w2'
        st.w = 0.f;
        lstat[r] = st;
    }

    // ---------------- phase 1c: x hi/lo split ----------------
    if (tid < 80) {
        float4 f = *(const float4*)&xs[tid << 2];
        const float* fp = (const float*)&f;
        unsigned wh[2], wl[2];
#pragma unroll
        for (int k = 0; k < 2; ++k) {
            unsigned ph = 0, pl = 0;
#pragma unroll
            for (int e = 0; e < 2; ++e) {
                float vv = fp[k * 2 + e];
                unsigned ub = __float_as_uint(vv);
                float hi = __uint_as_float(ub & 0xFFFF0000u);
                float lo = vv - hi;
                unsigned lb = __float_as_uint(lo);
                ph |= (e ? (ub & 0xFFFF0000u) : (ub >> 16));
                pl |= (e ? (lb & 0xFFFF0000u) : (lb >> 16));
            }
            wh[k] = ph; wl[k] = pl;
        }
        *(uint2*)&xh16[tid << 2] = make_uint2(wh[0], wh[1]);
        *(uint2*)&xl16[tid << 2] = make_uint2(wl[0], wl[1]);
    }
    __syncthreads();

    // ---------------- phase 2: MFMA main ----------------
    short8 Bh[4][2], Bl[4][2];
#pragma unroll
    for (int pt = 0; pt < 4; ++pt)
#pragma unroll
        for (int h = 0; h < 2; ++h) {
            Bh[pt][h] = *(const short8*)&Bhi[pt * 16 + n][h * 32 + (quad << 3)];
            Bl[pt][h] = *(const short8*)&Blo[pt * 16 + n][h * 32 + (quad << 3)];
        }
    const float4 sm4 = *(const float4*)&lsum[n << 2];   // logical 4n..4n+3
    const float4 sv4 = *(const float4*)&ls2[n << 2];    // *LOG2E already
    const unsigned* H = (const unsigned*)xh16;
    const unsigned* L = (const unsigned*)xl16;
    const unsigned shft = (n & 1) << 4;

#pragma unroll
    for (int u = 0; u < 4; ++u) {
        const int ab0 = (u << 6) + (wave << 4) + n + (quad << 3);
        short8 Ah[2], Al[2];
#pragma unroll
        for (int h = 0; h < 2; ++h) {
            const int i0 = (ab0 + (h << 5)) >> 1;
            unsigned dh[5], dl[5];
#pragma unroll
            for (int k = 0; k < 5; ++k) { dh[k] = H[i0 + k]; dl[k] = L[i0 + k]; }
            FragU fh, fl;
#pragma unroll
            for (int j = 0; j < 4; ++j) {
                fh.u[j] = funnel(dh[j + 1], dh[j], shft);
                fl.u[j] = funnel(dl[j + 1], dl[j], shft);
            }
            Ah[h] = fh.s; Al[h] = fl.s;
        }

        float4v acc[4];
#pragma unroll
        for (int pt = 0; pt < 4; ++pt) {
            float4v a = {0.f, 0.f, 0.f, 0.f};
#pragma unroll
            for (int h = 0; h < 2; ++h) {
                a = __builtin_amdgcn_mfma_f32_16x16x32_bf16(Ah[h], Bh[pt][h], a, 0, 0, 0);
                a = __builtin_amdgcn_mfma_f32_16x16x32_bf16(Ah[h], Bl[pt][h], a, 0, 0, 0);
                a = __builtin_amdgcn_mfma_f32_16x16x32_bf16(Al[h], Bh[pt][h], a, 0, 0, 0);
            }
            acc[pt] = a;
        }

        // epilogue (log2 domain): e = a'*acc - (amu'*sm + w2' + sv')
#pragma unroll
        for (int r = 0; r < 4; ++r) {
            int tl = (u << 6) + (wave << 4) + (quad << 2) + r;
            int tg = t0 + tl;
            float4 st = lstat[tl];
            float4 o;
            {
                float u0 = fmaf(st.y, sm4.x, st.z + sv4.x);
                float u1 = fmaf(st.y, sm4.y, st.z + sv4.y);
                float u2 = fmaf(st.y, sm4.z, st.z + sv4.z);
                float u3 = fmaf(st.y, sm4.w, st.z + sv4.w);
                o.x = __builtin_amdgcn_exp2f(fmaf(st.x, acc[0][r], -u0));
                o.y = __builtin_amdgcn_exp2f(fmaf(st.x, acc[1][r], -u1));
                o.z = __builtin_amdgcn_exp2f(fmaf(st.x, acc[2][r], -u2));
                o.w = __builtin_amdgcn_exp2f(fmaf(st.x, acc[3][r], -u3));
            }
            if (edge) {
                bool invalid = (tg < 32) || (tg > 8160);
                if (invalid) { o.x = 0.f; o.y = 0.f; o.z = 0.f; o.w = 0.f; }
            }
            *(float4*)(out + (((size_t)(b * T_LEN + tg)) << 6) + (n << 2)) = o;
        }
    }
}

extern "C" void kernel_launch(void* const* d_in, const int* in_sizes, int n_in,
                              void* d_out, int out_size, void* d_ws, size_t ws_size,
                              hipStream_t stream) {
    const float* x  = (const float*)d_in[0];   // (32, 8192, 1)
    const float* sh = (const float*)d_in[1];   // (64, 1, 64)
    float* out = (float*)d_out;                // (32, 8192, 64)

    shapelet_fused<<<32 * 32, 256, 0, stream>>>(x, sh, out);
}

// Round 9
// 82.336 us; speedup vs baseline: 1.0385x; 1.0385x over previous
//
#include <hip/hip_runtime.h>
#include <math.h>

#define T_LEN 8192
#define EPSF  1e-6f

typedef __attribute__((ext_vector_type(8))) short short8;
typedef __attribute__((ext_vector_type(4))) float float4v;

// ---------------------------------------------------------------------------
// R7 revert — measured best (82.0 us, absmax 2.584939e-26).
// One block = (batch b, 256-row t-strip), 1024 blocks, 256 threads,
// __launch_bounds__(256,4): exactly 4 blocks/CU, ONE dispatch round, no tail.
//
// Phase 0: stage raw shapelets (16 KB float4) -> Sraw; x window (320 f) -> xs.
// Phase 1: threads 0-63: serial two-pass znorm + bf16 hi/lo split per
//          shapelet (bit-identical arithmetic to R2..R7), written at permuted
//          B row c = (p&3)*16 + (p>>2). Threads 64-255: window stats for
//          rows 0..191; threads 64-127 additionally rows 192..255.
// Phase 2: B fragments -> registers (reused across FOUR 64-row units);
//          3-MFMA bf16 hi/lo GEMM; epilogue folds window znorm + exp,
//          direct float4 stores (lane n owns output cols 4n..4n+3).
//          Rows t<32 / t>8160 are the reference's zero padding.
// ---------------------------------------------------------------------------
__global__ __launch_bounds__(256, 4) void shapelet_fused(
        const float* __restrict__ x,
        const float* __restrict__ sh,
        float* __restrict__ out) {
    __shared__ float Sraw[64][65];             // 16.25 KB prep staging
    __shared__ unsigned short Bhi[64][72];     // 9 KB, 144 B rows
    __shared__ unsigned short Blo[64][72];     // 9 KB
    __shared__ float xs[320];                  // x[t0-32 .. t0+287]
    __shared__ float lmu[256], linv[256], lw2[256];   // 3 KB
    __shared__ __align__(16) float lsum[64];   // logical-p order
    __shared__ __align__(16) float ls2[64];

    const int tid  = threadIdx.x;
    const int lane = tid & 63;
    const int wave = tid >> 6;
    const int n    = lane & 15;
    const int quad = lane >> 4;

    const int super = blockIdx.x & 31;         // 32 strips of 256 rows
    const int b     = blockIdx.x >> 5;         // 32 batches
    const int t0    = super << 8;

    // ---------------- phase 0: staging ----------------
    {
        const float4* g4 = (const float4*)sh;  // 1024 float4 = 4096 floats
#pragma unroll
        for (int i = 0; i < 4; ++i) {
            int idx = tid + (i << 8);
            float4 v = g4[idx];
            int e = idx << 2;
            int row = e >> 6, col = e & 63;
            Sraw[row][col + 0] = v.x;
            Sraw[row][col + 1] = v.y;
            Sraw[row][col + 2] = v.z;
            Sraw[row][col + 3] = v.w;
        }
        if (tid < 80) {                        // 80 float4 = 320 floats
            int g0 = t0 - 32 + (tid << 2);
            float4 v;
            if (g0 >= 0 && g0 + 3 < T_LEN) {
                v = *(const float4*)(x + (size_t)b * T_LEN + g0);
            } else {
                float* vp = (float*)&v;
#pragma unroll
                for (int e = 0; e < 4; ++e) {
                    int g = g0 + e;
                    vp[e] = ((unsigned)g < (unsigned)T_LEN) ? x[(size_t)b * T_LEN + g] : 0.f;
                }
            }
            *(float4*)&xs[tid << 2] = v;
        }
    }
    __syncthreads();

    // ---------------- phase 1: in-block prep ----------------
    if (tid < 64) {
        // One thread per shapelet: EXACT R2..R7 prep arithmetic (serial).
        const int p = tid;
        const int c = ((p & 3) << 4) + (p >> 2);   // permuted B row
        float s1 = 0.f;
        for (int l = 0; l < 64; ++l) s1 += Sraw[p][l];
        float mu = s1 * (1.f / 64.f);
        float sq = 0.f;
        for (int l = 0; l < 64; ++l) { float d = Sraw[p][l] - mu; sq = fmaf(d, d, sq); }
        float sd  = fmaxf(sqrtf(sq * (1.f / 64.f)), EPSF);
        float inv = 1.f / sd;
        float ssum = 0.f, ss2 = 0.f;
        for (int l2 = 0; l2 < 32; ++l2) {
            unsigned pk_h, pk_l;
            {   // element 2*l2 (low half)
                float v = Sraw[p][2 * l2];
                float s = (v - mu) * inv;
                unsigned ub = __float_as_uint(s);
                float hi = __uint_as_float(ub & 0xFFFF0000u);
                float lo = s - hi;
                unsigned lb = __float_as_uint(lo) & 0xFFFF0000u;
                pk_h = ub >> 16;
                pk_l = lb >> 16;
                float eff = hi + __uint_as_float(lb);
                ssum += eff;
                ss2  = fmaf(eff, eff, ss2);
            }
            {   // element 2*l2+1 (high half)
                float v = Sraw[p][2 * l2 + 1];
                float s = (v - mu) * inv;
                unsigned ub = __float_as_uint(s);
                float hi = __uint_as_float(ub & 0xFFFF0000u);
                float lo = s - hi;
                unsigned lb = __float_as_uint(lo) & 0xFFFF0000u;
                pk_h |= (ub & 0xFFFF0000u);
                pk_l |= lb;
                float eff = hi + __uint_as_float(lb);
                ssum += eff;
                ss2  = fmaf(eff, eff, ss2);
            }
            *(unsigned*)&Bhi[c][2 * l2] = pk_h;
            *(unsigned*)&Blo[c][2 * l2] = pk_l;
        }
        lsum[p] = ssum;
        ls2[p]  = ss2;
    } else {
        // per-row window stats (verbatim math); threads 64-255 -> rows 0-191,
        // threads 64-127 additionally rows 192-255.
        int r = tid - 64;
#pragma unroll
        for (int pass = 0; pass < 2; ++pass) {
            if (pass == 0 || r < 64 + 192) {   // second pass only for tid<128
                float s1 = 0.f, sq = 0.f;
#pragma unroll
                for (int l = 0; l < 64; ++l) {
                    float v = xs[r + l];
                    s1 += v; sq = fmaf(v, v, sq);
                }
                float mu  = s1 * (1.f / 64.f);
                float var = fmaxf(sq * (1.f / 64.f) - mu * mu, 0.f);
                float sd  = fmaxf(sqrtf(var), EPSF);
                float inv = 1.f / sd;
                lmu[r]  = mu;
                linv[r] = inv;
                lw2[r]  = 64.f * var * inv * inv;
            }
            if (tid >= 128) break;
            r = tid - 64 + 192;                // rows 192..255
            if (pass == 1) break;
        }
    }
    __syncthreads();

    // ---------------- phase 2: MFMA main ----------------
    // B-operand layout: lane holds B[k = quad*8+j + 32*h][col = lane&15];
    // permuted B row c = pt*16+n is logical shapelet 4n+pt.
    short8 Bh[4][2], Bl[4][2];
#pragma unroll
    for (int pt = 0; pt < 4; ++pt)
#pragma unroll
        for (int h = 0; h < 2; ++h) {
            Bh[pt][h] = *(const short8*)&Bhi[pt * 16 + n][h * 32 + (quad << 3)];
            Bl[pt][h] = *(const short8*)&Blo[pt * 16 + n][h * 32 + (quad << 3)];
        }
    const float4 sm4 = *(const float4*)&lsum[n << 2];   // logical 4n..4n+3
    const float4 sv4 = *(const float4*)&ls2[n << 2];

#pragma unroll
    for (int u = 0; u < 4; ++u) {
        // A fragments: A[m][k] = xs[u*64 + wave*16 + m + k]
        const int abase = (u << 6) + (wave << 4) + n + (quad << 3);
        short8 Ah[2], Al[2];
#pragma unroll
        for (int h = 0; h < 2; ++h) {
#pragma unroll
            for (int j = 0; j < 8; ++j) {
                float v = xs[abase + h * 32 + j];
                unsigned ub = __float_as_uint(v);
                unsigned hb = ub & 0xFFFF0000u;
                float lo = v - __uint_as_float(hb);
                Ah[h][j] = (short)(ub >> 16);
                Al[h][j] = (short)(__float_as_uint(lo) >> 16);
            }
        }

        float4v acc[4];
#pragma unroll
        for (int pt = 0; pt < 4; ++pt) {
            float4v a = {0.f, 0.f, 0.f, 0.f};
#pragma unroll
            for (int h = 0; h < 2; ++h) {
                a = __builtin_amdgcn_mfma_f32_16x16x32_bf16(Ah[h], Bh[pt][h], a, 0, 0, 0);
                a = __builtin_amdgcn_mfma_f32_16x16x32_bf16(Ah[h], Bl[pt][h], a, 0, 0, 0);
                a = __builtin_amdgcn_mfma_f32_16x16x32_bf16(Al[h], Bh[pt][h], a, 0, 0, 0);
            }
            acc[pt] = a;
        }

        // epilogue: fold window znorm + exp, float4 store at cols 4n..4n+3
#pragma unroll
        for (int r = 0; r < 4; ++r) {
            // C/D layout: col = lane&15, row = quad*4 + r
            int tl = (u << 6) + (wave << 4) + (quad << 2) + r;
            int tg = t0 + tl;
            bool valid = (tg >= 32) && (tg <= 8160);
            float mu  = lmu[tl];
            float inv = linv[tl];
            float w2  = lw2[tl];
            float d0 = (acc[0][r] - mu * sm4.x) * inv;
            float d1 = (acc[1][r] - mu * sm4.y) * inv;
            float d2 = (acc[2][r] - mu * sm4.z) * inv;
            float d3 = (acc[3][r] - mu * sm4.w) * inv;
            float4 o;
            o.x = valid ? __expf(-(w2 + sv4.x - 2.f * d0)) : 0.f;
            o.y = valid ? __expf(-(w2 + sv4.y - 2.f * d1)) : 0.f;
            o.z = valid ? __expf(-(w2 + sv4.z - 2.f * d2)) : 0.f;
            o.w = valid ? __expf(-(w2 + sv4.w - 2.f * d3)) : 0.f;
            *(float4*)(out + (((size_t)(b * T_LEN + tg)) << 6) + (n << 2)) = o;
        }
    }
}

extern "C" void kernel_launch(void* const* d_in, const int* in_sizes, int n_in,
                              void* d_out, int out_size, void* d_ws, size_t ws_size,
                              hipStream_t stream) {
    const float* x  = (const float*)d_in[0];   // (32, 8192, 1)
    const float* sh = (const float*)d_in[1];   // (64, 1, 64)
    float* out = (float*)d_out;                // (32, 8192, 64)

    shapelet_fused<<<32 * 32, 256, 0, stream>>>(x, sh, out);
}